// Round 7
// baseline (684.559 us; speedup 1.0000x reference)
//
#include <hip/hip_runtime.h>

// Problem constants (B=2, H=16, L=2048, D=64 — fixed by the reference setup).
#define BH   32
#define LSEQ 2048
#define DDIM 64
#define ERRC 1e-12f
#define SROW2 260  // phase-2 LDS strip stride (256 cols + 4 pad), floats

typedef __attribute__((ext_vector_type(8)))  short bf16x8;
typedef __attribute__((ext_vector_type(4)))  float floatx4;
typedef __attribute__((ext_vector_type(4)))  unsigned short ushort4v;

// float -> bf16 round-to-nearest-even (inputs are finite, no NaN handling needed)
__device__ __forceinline__ unsigned short f2bf(float f) {
    unsigned u = __float_as_uint(f);
    u = u + 0x7FFFu + ((u >> 16) & 1u);
    return (unsigned short)(u >> 16);
}

__device__ __forceinline__ bf16x8 pack8s(const float* __restrict__ p, float w) {
    const floatx4* pv = (const floatx4*)p;
    floatx4 x = pv[0], y = pv[1];
    bf16x8 r;
    r[0] = (short)f2bf(x[0] * w); r[1] = (short)f2bf(x[1] * w);
    r[2] = (short)f2bf(x[2] * w); r[3] = (short)f2bf(x[3] * w);
    r[4] = (short)f2bf(y[0] * w); r[5] = (short)f2bf(y[1] * w);
    r[6] = (short)f2bf(y[2] * w); r[7] = (short)f2bf(y[3] * w);
    return r;
}

// Prep: ks = bf16(k * sqrt(src+err)), kd = bf16(k * sqrt(dest+err)).
__global__ __launch_bounds__(256) void prep_scaled(const float* __restrict__ k,
                                                   const float* __restrict__ src,
                                                   const float* __restrict__ dest,
                                                   unsigned short* __restrict__ ks,
                                                   unsigned short* __restrict__ kd) {
    int idx4 = blockIdx.x * 256 + threadIdx.x;
    int row  = idx4 >> 4;                     // 16 float4 per 64-wide row
    float s = sqrtf(src[row] + ERRC);
    float d = sqrtf(dest[row] + ERRC);
    floatx4 v = ((const floatx4*)k)[idx4];
    ushort4v os, od;
#pragma unroll
    for (int r = 0; r < 4; ++r) { os[r] = f2bf(v[r] * s); od[r] = f2bf(v[r] * d); }
    ((ushort4v*)ks)[idx4] = os;
    ((ushort4v*)kd)[idx4] = od;
}

__device__ __forceinline__ void load_frag(const unsigned short* __restrict__ p,
                                          bf16x8& lo, bf16x8& hi) {
    lo = *(const bf16x8*)p;
    hi = *(const bf16x8*)(p + 32);
}

// ---------------------------------------------------------------------------
// Phase 1: per-row 512-wide strip sums S[row][c], c = 0..2 (chunk 3's sum is
// never consumed). One wave = 16 i-rows, walks j = 0..1536. No output stores.
// MFMA layout (swapped): D[m=j_local][n=i_local]; col(l16)=i, row(q*4+r)=j.
// ---------------------------------------------------------------------------
__global__ __launch_bounds__(256, 4) void strip_sums(const unsigned short* __restrict__ kd,
                                                     const unsigned short* __restrict__ ks,
                                                     float* __restrict__ S) {
    const int tid  = threadIdx.x;
    const int wave = tid >> 6;
    const int lane = tid & 63;
    const int q    = lane >> 4;
    const int l16  = lane & 15;
    const int bh   = blockIdx.x & 31;         // same bh -> same XCD under mod-8 dispatch
    const int ib   = blockIdx.x >> 5;         // 0..31
    const int i0   = (ib * 4 + wave) * 16;
    const int bhL  = bh * LSEQ;
    const unsigned short* kdb = kd + (long)bh * LSEQ * DDIM;
    const unsigned short* ksb = ks + (long)bh * LSEQ * DDIM;

    bf16x8 blo, bhi;
    load_frag(ksb + (long)(i0 + l16) * DDIM + q * 8, blo, bhi);

    bf16x8 aLo[4], aHi[4];
#pragma unroll
    for (int t = 0; t < 4; ++t)
        load_frag(kdb + (long)(16 * t + l16) * DDIM + q * 8, aLo[t], aHi[t]);

    const float c23 = 2.0f / 3.0f;
    float ssv[3];

    for (int cc = 0; cc < 3; ++cc) {
        float ss = 0.f;
        for (int g = 0; g < 8; ++g) {
            const int jn = (cc * 8 + g < 23) ? (cc * 512 + g * 64 + 64) : 0;
            bf16x8 nLo[4], nHi[4];
#pragma unroll
            for (int t = 0; t < 4; ++t)
                load_frag(kdb + (long)(jn + 16 * t + l16) * DDIM + q * 8, nLo[t], nHi[t]);

            floatx4 acc[4];
#pragma unroll
            for (int t = 0; t < 4; ++t) {
                floatx4 z4 = {0.f, 0.f, 0.f, 0.f};
                z4 = __builtin_amdgcn_mfma_f32_16x16x32_bf16(aLo[t], blo, z4, 0, 0, 0);
                acc[t] = __builtin_amdgcn_mfma_f32_16x16x32_bf16(aHi[t], bhi, z4, 0, 0, 0);
            }

            float s = 0.f;
#pragma unroll
            for (int t = 0; t < 4; ++t)
#pragma unroll
                for (int r = 0; r < 4; ++r) {
                    float v = fmaxf(acc[t][r], 0.f) + ERRC;
                    s += exp2f(c23 * __log2f(v));
                }
            float s1 = s + __shfl_xor(s, 16, 64);
            ss += s1 + __shfl_xor(s1, 32, 64);

#pragma unroll
            for (int t = 0; t < 4; ++t) { aLo[t] = nLo[t]; aHi[t] = nHi[t]; }
        }
        ssv[cc] = ss;
    }

    // lane (q, l16): q<3 stores chunk q's sum for row i0+l16
    float sv = (q == 0) ? ssv[0] : (q == 1) ? ssv[1] : ssv[2];
    if (q < 3)
        S[(long)(bhL + i0 + l16) * 4 + q] = sv;
}

// ---------------------------------------------------------------------------
// Phase 2: one wave = 16 i-rows x one 512-j chunk. Starting carry comes from
// the strip-sum prefix, so chunks are independent -> each row's 2KB segment is
// written ONCE, time-compressed, as 1KB-contiguous single instructions.
// Fully-masked chunks (37.5% of area) are pure sequential zero-fill.
// ---------------------------------------------------------------------------
__global__ __launch_bounds__(128, 2) void chunk_out(const unsigned short* __restrict__ kd,
                                                    const unsigned short* __restrict__ ks,
                                                    const float* __restrict__ S,
                                                    float* __restrict__ out) {
    __shared__ float strip[2][16 * SROW2];    // 16.6 KiB per wave, wave-private
    const int tid  = threadIdx.x;
    const int wave = tid >> 6;                // 0..1
    const int lane = tid & 63;
    const int q    = lane >> 4;
    const int l16  = lane & 15;
    const int bh   = blockIdx.x & 31;         // same bh -> same XCD under mod-8 dispatch
    const int rr   = blockIdx.x >> 5;         // 0..255
    const int ib2  = rr & 63;                 // 0..63
    const int c    = rr >> 6;                 // 0..3 (j chunk)
    const int i0   = (ib2 * 2 + wave) * 16;
    const int bhL  = bh * LSEQ;
    const int jb   = c << 9;                  // chunk base (512 cols)

    if (jb + 512 <= i0) {
        // fully masked chunk: sequential zero-fill, 1KB contiguous per instruction
        const floatx4 z = {0.f, 0.f, 0.f, 0.f};
#pragma unroll
        for (int s = 0; s < 16; ++s) {
            float* row = out + (long)(bhL + i0 + s) * LSEQ + jb + 4 * lane;
            *(floatx4*)row = z;
            *(floatx4*)(row + 256) = z;
        }
        return;
    }

    const unsigned short* kdb = kd + (long)bh * LSEQ * DDIM;
    const unsigned short* ksb = ks + (long)bh * LSEQ * DDIM;
    float* sw = strip[wave];

    bf16x8 blo, bhi;
    load_frag(ksb + (long)(i0 + l16) * DDIM + q * 8, blo, bhi);

    // starting carry for row i0+l16 = sum of preceding strip sums
    float carry = 0.f;
    const float* Sr = S + (long)(bhL + i0 + l16) * 4;
#pragma unroll
    for (int cc = 0; cc < 3; ++cc)
        if (cc < c) carry += Sr[cc];

    const float c23 = 2.0f / 3.0f;

    bf16x8 aLo[4], aHi[4];
#pragma unroll
    for (int t = 0; t < 4; ++t)
        load_frag(kdb + (long)(jb + 16 * t + l16) * DDIM + q * 8, aLo[t], aHi[t]);

    for (int hh = 0; hh < 2; ++hh) {
#pragma unroll
        for (int gg = 0; gg < 4; ++gg) {
            const int colbase = gg * 64;
            const int j0 = jb + hh * 256 + colbase;
            const int jl = hh * 256 + colbase + 64;
            const int jn = jb + ((jl < 512) ? jl : 0);

            bf16x8 nLo[4], nHi[4];
#pragma unroll
            for (int t = 0; t < 4; ++t)
                load_frag(kdb + (long)(jn + 16 * t + l16) * DDIM + q * 8, nLo[t], nHi[t]);

            floatx4 acc[4];
#pragma unroll
            for (int t = 0; t < 4; ++t) {
                floatx4 z4 = {0.f, 0.f, 0.f, 0.f};
                z4 = __builtin_amdgcn_mfma_f32_16x16x32_bf16(aLo[t], blo, z4, 0, 0, 0);
                acc[t] = __builtin_amdgcn_mfma_f32_16x16x32_bf16(aHi[t], bhi, z4, 0, 0, 0);
            }

            float u[4][4];
#pragma unroll
            for (int t = 0; t < 4; ++t)
#pragma unroll
                for (int r = 0; r < 4; ++r) {
                    float v = fmaxf(acc[t][r], 0.f) + ERRC;
                    u[t][r] = exp2f(c23 * __log2f(v));
                }

            if (j0 + 64 <= i0) {
                // fully masked group: only totals feed the carry; stage zeros
                float s = 0.f;
#pragma unroll
                for (int t = 0; t < 4; ++t)
                    s += (u[t][0] + u[t][1]) + (u[t][2] + u[t][3]);
                float s1 = s + __shfl_xor(s, 16, 64);
                carry += s1 + __shfl_xor(s1, 32, 64);
                const floatx4 z = {0.f, 0.f, 0.f, 0.f};
#pragma unroll
                for (int t = 0; t < 4; ++t)
                    *(floatx4*)&sw[l16 * SROW2 + colbase + 16 * t + 4 * q] = z;
            } else {
#pragma unroll
                for (int t = 0; t < 4; ++t) {
                    const int jt0 = j0 + 16 * t;
                    float* dst = &sw[l16 * SROW2 + colbase + 16 * t + 4 * q];
                    if (jt0 + 16 <= i0) {
                        float s = (u[t][0] + u[t][1]) + (u[t][2] + u[t][3]);
                        float s1 = s + __shfl_xor(s, 16, 64);
                        carry += s1 + __shfl_xor(s1, 32, 64);
                        const floatx4 z = {0.f, 0.f, 0.f, 0.f};
                        *(floatx4*)dst = z;
                    } else {
                        // in-lane inclusive prefix over this lane's 4 consecutive j
                        u[t][1] += u[t][0];
                        u[t][2] += u[t][1];
                        u[t][3] += u[t][2];
                        const float Sg  = u[t][3];
                        const float x16 = __shfl_xor(Sg, 16, 64);
                        const float s1  = Sg + x16;
                        const float x32 = __shfl_xor(s1, 32, 64);
                        const float E = ((q & 1) ? x16 : 0.f) + ((q & 2) ? x32 : 0.f) + carry;
                        carry += s1 + x32;
                        floatx4 o;
                        if (jt0 == i0) {  // the single mixed (diagonal) tile
#pragma unroll
                            for (int r = 0; r < 4; ++r)
                                o[r] = ((q * 4 + r) >= l16) ? (u[t][r] + E) : 0.f;
                        } else {          // fully above diagonal
#pragma unroll
                            for (int r = 0; r < 4; ++r)
                                o[r] = u[t][r] + E;
                        }
                        *(floatx4*)dst = o;
                    }
                }
            }

#pragma unroll
            for (int t = 0; t < 4; ++t) { aLo[t] = nLo[t]; aHi[t] = nHi[t]; }
        }

        // flush this 256-col half: 16 instrs, each one FULL row segment of 1KB
#pragma unroll
        for (int s = 0; s < 16; ++s) {
            floatx4 v = *(const floatx4*)&sw[s * SROW2 + 4 * lane];
            *(floatx4*)(out + (long)(bhL + i0 + s) * LSEQ + jb + hh * 256 + 4 * lane) = v;
        }
    }
}

// ---------------------------------------------------------------------------
// Fallback (workspace too small): single-pass kernel reading raw fp32 k
// (round-3 structure, harness-proven). Correct but slower.
// ---------------------------------------------------------------------------
__device__ __forceinline__ void load_row16_raw(const float* __restrict__ kp, long base, int row,
                                               int q, const float* __restrict__ w, int bhL,
                                               bf16x8& lo, bf16x8& hi) {
    const float* p = kp + base + (long)row * DDIM + q * 8;
    float s = sqrtf(w[bhL + row] + ERRC);
    lo = pack8s(p, s);
    hi = pack8s(p + 32, s);
}

__global__ __launch_bounds__(256, 4) void mha_raw(const float* __restrict__ kp,
                                                  const float* __restrict__ src,
                                                  const float* __restrict__ dest,
                                                  float* __restrict__ out) {
    const int tid  = threadIdx.x;
    const int wave = tid >> 6;
    const int lane = tid & 63;
    const int q    = lane >> 4;
    const int l16  = lane & 15;
    const int bh = blockIdx.x & 31;
    const int ib = blockIdx.x >> 5;
    const int i0 = (ib * 4 + wave) * 16;
    const int bhL = bh * LSEQ;
    const long base = (long)bh * LSEQ * DDIM;

    bf16x8 blo, bhi;
    load_row16_raw(kp, base, i0 + l16, q, src, bhL, blo, bhi);

    float carry = 0.f;
    const float c23 = 2.0f / 3.0f;

    bf16x8 aLo[4], aHi[4];
#pragma unroll
    for (int t = 0; t < 4; ++t)
        load_row16_raw(kp, base, 16 * t + l16, q, dest, bhL, aLo[t], aHi[t]);

    float* orow = out + (long)(bhL + i0 + l16) * LSEQ + q * 4;

    for (int it = 0; it < 32; ++it) {
        const int j0 = it << 6;
        bf16x8 nLo[4], nHi[4];
        const int jn = (it < 31) ? (j0 + 64) : 0;
#pragma unroll
        for (int t = 0; t < 4; ++t)
            load_row16_raw(kp, base, jn + 16 * t + l16, q, dest, bhL, nLo[t], nHi[t]);

        floatx4 acc[4];
#pragma unroll
        for (int t = 0; t < 4; ++t) {
            floatx4 z4 = {0.f, 0.f, 0.f, 0.f};
            z4 = __builtin_amdgcn_mfma_f32_16x16x32_bf16(aLo[t], blo, z4, 0, 0, 0);
            acc[t] = __builtin_amdgcn_mfma_f32_16x16x32_bf16(aHi[t], bhi, z4, 0, 0, 0);
        }

        float u[4][4];
#pragma unroll
        for (int t = 0; t < 4; ++t)
#pragma unroll
            for (int r = 0; r < 4; ++r) {
                float v = fmaxf(acc[t][r], 0.f) + ERRC;
                u[t][r] = exp2f(c23 * __log2f(v));
            }

#pragma unroll
        for (int t = 0; t < 4; ++t) {
            const int jt0 = j0 + 16 * t;
            if (jt0 + 16 <= i0) {
                float s = (u[t][0] + u[t][1]) + (u[t][2] + u[t][3]);
                float s1 = s + __shfl_xor(s, 16, 64);
                carry += s1 + __shfl_xor(s1, 32, 64);
                const floatx4 z = {0.f, 0.f, 0.f, 0.f};
                *(floatx4*)(orow + jt0) = z;
            } else {
                u[t][1] += u[t][0];
                u[t][2] += u[t][1];
                u[t][3] += u[t][2];
                const float Sg  = u[t][3];
                const float x16 = __shfl_xor(Sg, 16, 64);
                const float s1  = Sg + x16;
                const float x32 = __shfl_xor(s1, 32, 64);
                const float E = ((q & 1) ? x16 : 0.f) + ((q & 2) ? x32 : 0.f) + carry;
                carry += s1 + x32;
                floatx4 o;
                if (jt0 == i0) {
#pragma unroll
                    for (int r = 0; r < 4; ++r)
                        o[r] = ((q * 4 + r) >= l16) ? (u[t][r] + E) : 0.f;
                } else {
#pragma unroll
                    for (int r = 0; r < 4; ++r)
                        o[r] = u[t][r] + E;
                }
                *(floatx4*)(orow + jt0) = o;
            }
        }

#pragma unroll
        for (int t = 0; t < 4; ++t) { aLo[t] = nLo[t]; aHi[t] = nHi[t]; }
    }
}

extern "C" void kernel_launch(void* const* d_in, const int* in_sizes, int n_in,
                              void* d_out, int out_size, void* d_ws, size_t ws_size,
                              hipStream_t stream) {
    const float* k    = (const float*)d_in[0];
    const float* src  = (const float*)d_in[1];
    const float* dest = (const float*)d_in[2];
    float* out = (float*)d_out;

    const size_t half = (size_t)BH * LSEQ * DDIM * sizeof(unsigned short); // 8 MiB
    const size_t ssz  = (size_t)BH * LSEQ * 4 * sizeof(float);             // 1 MiB
    if (ws_size >= 2 * half + ssz) {
        unsigned short* ks = (unsigned short*)d_ws;
        unsigned short* kd = (unsigned short*)((char*)d_ws + half);
        float* S = (float*)((char*)d_ws + 2 * half);
        prep_scaled<<<dim3(4096), dim3(256), 0, stream>>>(k, src, dest, ks, kd);
        strip_sums<<<dim3(1024), dim3(256), 0, stream>>>(kd, ks, S);
        chunk_out<<<dim3(8192), dim3(128), 0, stream>>>(kd, ks, S, out);
    } else {
        mha_raw<<<dim3(1024), dim3(256), 0, stream>>>(k, src, dest, out);
    }
}